// Round 1
// baseline (206.225 us; speedup 1.0000x reference)
//
#include <hip/hip_runtime.h>
#include <stdint.h>

// SAGAN self-attention, MI355X gfx950.
// B=8, C=256, CK=32, N=4096. fp32 in/out, bf16 MFMA internally.

typedef __bf16 bf16;
typedef __bf16 bf16x8 __attribute__((ext_vector_type(8)));
typedef float  f32x16 __attribute__((ext_vector_type(16)));

#define BATCH 8
#define CC    256
#define CKK   32
#define NN    4096
#define LOG2E 1.4426950408889634f

__device__ __forceinline__ f32x16 zero16() {
  f32x16 z;
#pragma unroll
  for (int i = 0; i < 16; ++i) z[i] = 0.0f;
  return z;
}

__device__ __forceinline__ unsigned pack2(float lo, float hi) {
  unsigned short a = __builtin_bit_cast(unsigned short, (bf16)lo);
  unsigned short b = __builtin_bit_cast(unsigned short, (bf16)hi);
  return (unsigned)a | ((unsigned)b << 16);
}

__device__ __forceinline__ f32x16 mfma32(bf16x8 a, bf16x8 b, f32x16 c) {
  return __builtin_amdgcn_mfma_f32_32x32x16_bf16(a, b, c, 0, 0, 0);
}

#define GLDS16(srcp, dstp)                                                         \
  __builtin_amdgcn_global_load_lds(                                               \
      (const __attribute__((address_space(1))) void*)(srcp),                      \
      (__attribute__((address_space(3))) void*)(dstp), 16, 0, 0)

// ---------------- kernel 0a: x f32 [B][C][N] -> xT bf16 [B][N][C] ----------------
__global__ __launch_bounds__(256) void k_transpose(const float* __restrict__ x,
                                                   bf16* __restrict__ xT) {
  __shared__ float tile[64][65];
  const int n0 = blockIdx.x * 64;
  const int c0 = blockIdx.y * 64;
  const int b  = blockIdx.z;
  const int t = threadIdx.x;
  const int tn = t & 63, trow = t >> 6;
#pragma unroll
  for (int i = 0; i < 16; ++i) {
    int c = trow + i * 4;
    tile[c][tn] = x[((size_t)(b * CC + c0 + c)) * NN + n0 + tn];
  }
  __syncthreads();
#pragma unroll
  for (int i = 0; i < 16; ++i) {
    int n = trow + i * 4;
    xT[((size_t)(b * NN + n0 + n)) * CC + c0 + tn] = (bf16)tile[tn][n];
  }
}

// ---------------- kernel 0b: weight pack ----------------
// Wcat bf16 [320][256]: rows 0..31 = Wf, 32..63 = Wg*log2e, 64..319 = Wh.
// bcat f32 [320] likewise (bg scaled by log2e).
__global__ __launch_bounds__(64) void k_wprep(const float* __restrict__ Wf, const float* __restrict__ bfv,
                                              const float* __restrict__ Wg, const float* __restrict__ bg,
                                              const float* __restrict__ Wh, const float* __restrict__ bh,
                                              bf16* __restrict__ Wcat, float* __restrict__ bcat) {
  const int ko = blockIdx.x;  // 0..319
  const int t = threadIdx.x;
  const float* src;
  float scale = 1.0f;
  if (ko < 32) src = Wf + (size_t)ko * CC;
  else if (ko < 64) { src = Wg + (size_t)(ko - 32) * CC; scale = LOG2E; }
  else src = Wh + (size_t)(ko - 64) * CC;
#pragma unroll
  for (int i = 0; i < 4; ++i)
    Wcat[(size_t)ko * CC + t + i * 64] = (bf16)(src[t + i * 64] * scale);
  if (ko == 0) {
    for (int i = t; i < 320; i += 64) {
      float v = (i < 32) ? bfv[i] : (i < 64) ? bg[i - 32] * LOG2E : bh[i - 64];
      bcat[i] = v;
    }
  }
}

// ---------------- kernel 1: projections (MFMA GEMM 320x256 @ x) ----------------
// fxT/gxT: bf16 [B][N][32]  (row-per-pixel, K-major for attention frag loads)
// hx:      bf16 [B][C][N]
__global__ __launch_bounds__(256, 1) void k_proj(const bf16* __restrict__ xT,
                                                 const bf16* __restrict__ Wcat,
                                                 const float* __restrict__ bcat,
                                                 bf16* __restrict__ fxT, bf16* __restrict__ gxT,
                                                 bf16* __restrict__ hx) {
  const int d = blockIdx.x;
  const int b = d & 7, nb = d >> 3;          // batch -> XCD alignment
  const int t = threadIdx.x;
  const int w = t >> 6, ln = t & 63, ln31 = ln & 31, h = ln >> 5;
  const int n = nb * 128 + w * 32 + ln31;    // this lane's output column

  f32x16 acc[10];
#pragma unroll
  for (int mt = 0; mt < 10; ++mt) acc[mt] = zero16();

  const bf16* xrow = xT + ((size_t)(b * NN + n)) * CC;
#pragma unroll
  for (int ks = 0; ks < 16; ++ks) {
    bf16x8 bfrag = *(const bf16x8*)(xrow + ks * 16 + h * 8);  // B[k=c][n]
#pragma unroll
    for (int mt = 0; mt < 10; ++mt) {
      bf16x8 afrag = *(const bf16x8*)(Wcat + (size_t)(mt * 32 + ln31) * CC + ks * 16 + h * 8);
      acc[mt] = mfma32(afrag, bfrag, acc[mt]);
    }
  }

#pragma unroll
  for (int mt = 0; mt < 10; ++mt) {
#pragma unroll
    for (int q = 0; q < 4; ++q) {
      const int ko0 = mt * 32 + 8 * q + 4 * h;  // rows ko0..ko0+3
      float v0 = acc[mt][4 * q + 0] + bcat[ko0 + 0];
      float v1 = acc[mt][4 * q + 1] + bcat[ko0 + 1];
      float v2 = acc[mt][4 * q + 2] + bcat[ko0 + 2];
      float v3 = acc[mt][4 * q + 3] + bcat[ko0 + 3];
      if (mt < 2) {
        bf16* dst = (mt == 0 ? fxT : gxT) + ((size_t)(b * NN + n)) * CKK + (8 * q + 4 * h);
        uint2 pv;
        pv.x = pack2(v0, v1);
        pv.y = pack2(v2, v3);
        *(uint2*)dst = pv;
      } else {
        const int c = ko0 - 64;
        hx[((size_t)(b * CC + c + 0)) * NN + n] = (bf16)v0;
        hx[((size_t)(b * CC + c + 1)) * NN + n] = (bf16)v1;
        hx[((size_t)(b * CC + c + 2)) * NN + n] = (bf16)v2;
        hx[((size_t)(b * CC + c + 3)) * NN + n] = (bf16)v3;
      }
    }
  }
}

// ---------------- kernel 2: flash attention ----------------
// Grid 256 (b = blk&7 -> XCD-local V). Block = 4 waves, 32 queries each.
// Per 64-key block: S = K·Q (2x2 mfma), online softmax (log2 domain, defer-max),
// in-register P transpose via shfl_xor(32), O += V·P (8x4 mfma).
__global__ __launch_bounds__(256, 1) void k_attn(const bf16* __restrict__ fxT,
                                                 const bf16* __restrict__ gxT,
                                                 const bf16* __restrict__ hx,
                                                 const float* __restrict__ x,
                                                 const float* __restrict__ gammap,
                                                 float* __restrict__ out) {
  __shared__ __align__(16) bf16 vbuf[2][16384];  // 2 x 32KB V tiles [256 c][64 i], chunk-swizzled
  const int d = blockIdx.x;
  const int b = d & 7, jb = d >> 3;
  const int t = threadIdx.x;
  const int w = t >> 6, ln = t & 63, ln31 = ln & 31, h = ln >> 5;
  const int j = jb * 128 + w * 32 + ln31;

  const bf16* fxb = fxT + (size_t)b * NN * CKK;
  const bf16* hxb = hx + (size_t)b * CC * NN;

  const bf16* qrow = gxT + ((size_t)b * NN + j) * CKK;
  bf16x8 qf0 = *(const bf16x8*)(qrow + h * 8);        // ck 0..15 half (per-lane)
  bf16x8 qf1 = *(const bf16x8*)(qrow + 16 + h * 8);   // ck 16..31

  f32x16 oacc[8];
#pragma unroll
  for (int ct = 0; ct < 8; ++ct) oacc[ct] = zero16();
  float m_ref = -__builtin_inff();
  float l_run = 0.0f;

  // per-lane swizzled V-frag offsets (elements): row=ln31, phys chunk=(2kk+h)^(ln31&7)
  int voff[4];
#pragma unroll
  for (int kk = 0; kk < 4; ++kk)
    voff[kk] = ln31 * 64 + (((2 * kk + h) ^ (ln31 & 7)) * 8);

  // prologue: stage key-block 0 (pre-swizzled global source, linear LDS dest)
#pragma unroll
  for (int q = 0; q < 8; ++q) {
    int f = q * 256 + t;
    int row = f >> 3;
    int lc = (f & 7) ^ (row & 7);
    const bf16* src = hxb + (size_t)row * NN + lc * 8;
    bf16* dst = &vbuf[0][(q * 256 + (t & 192)) * 8];
    GLDS16(src, dst);
  }
  asm volatile("s_waitcnt vmcnt(0)" ::: "memory");
  __syncthreads();

  for (int kb = 0; kb < 64; ++kb) {
    const int i0 = kb * 64;

    // K fragments first (oldest loads -> compiler waits leave staging outstanding)
    const bf16* kr0 = fxb + ((size_t)(i0 + ln31)) * CKK;
    const bf16* kr1 = fxb + ((size_t)(i0 + 32 + ln31)) * CKK;
    bf16x8 kf00 = *(const bf16x8*)(kr0 + h * 8);
    bf16x8 kf01 = *(const bf16x8*)(kr0 + 16 + h * 8);
    bf16x8 kf10 = *(const bf16x8*)(kr1 + h * 8);
    bf16x8 kf11 = *(const bf16x8*)(kr1 + 16 + h * 8);

    // async-stage next key-block into the other buffer
    if (kb < 63) {
      bf16* nbuf = &vbuf[(kb + 1) & 1][0];
#pragma unroll
      for (int q = 0; q < 8; ++q) {
        int f = q * 256 + t;
        int row = f >> 3;
        int lc = (f & 7) ^ (row & 7);
        const bf16* src = hxb + (size_t)row * NN + (i0 + 64) + lc * 8;
        bf16* dst = nbuf + (q * 256 + (t & 192)) * 8;
        GLDS16(src, dst);
      }
    }
    const bf16* vb = &vbuf[kb & 1][0];

    // S[i,j] = <fx_i, gx_j> (already in log2 domain via pre-scaled Wg)
    f32x16 s0 = zero16(), s1 = zero16();
    s0 = mfma32(kf00, qf0, s0);
    s0 = mfma32(kf01, qf1, s0);
    s1 = mfma32(kf10, qf0, s1);
    s1 = mfma32(kf11, qf1, s1);

    // block max over all 64 keys for this j (4 h-halves: lane l and l^32 share j)
    float smax = -__builtin_inff();
#pragma unroll
    for (int r = 0; r < 16; ++r) {
      smax = fmaxf(smax, s0[r]);
      smax = fmaxf(smax, s1[r]);
    }
    smax = fmaxf(smax, __shfl_xor(smax, 32));

    // defer-max rescale (THR=8 in exp2 domain -> P <= 256, bf16-safe)
    bool need = smax > m_ref + 8.0f;
    if (__any(need)) {
      float rr = need ? __builtin_exp2f(m_ref - smax) : 1.0f;
      if (need) m_ref = smax;
      l_run *= rr;
#pragma unroll
      for (int ct = 0; ct < 8; ++ct)
#pragma unroll
        for (int r = 0; r < 16; ++r) oacc[ct][r] *= rr;
    }

    // P = exp2(S - m_ref), pack to bf16 pairs
    float lsum = 0.0f;
    unsigned pk0[4][2], pk1[4][2];
#pragma unroll
    for (int q = 0; q < 4; ++q) {
#pragma unroll
      for (int wi = 0; wi < 2; ++wi) {
        float a0 = __builtin_exp2f(s0[4 * q + 2 * wi] - m_ref);
        float a1 = __builtin_exp2f(s0[4 * q + 2 * wi + 1] - m_ref);
        float b0 = __builtin_exp2f(s1[4 * q + 2 * wi] - m_ref);
        float b1 = __builtin_exp2f(s1[4 * q + 2 * wi + 1] - m_ref);
        lsum += (a0 + a1) + (b0 + b1);
        pk0[q][wi] = pack2(a0, a1);
        pk1[q][wi] = pack2(b0, b1);
      }
    }
    lsum += __shfl_xor(lsum, 32);
    l_run += lsum;

    // in-register transpose: S-frag (rows 4-interleaved) -> PV B-frag (rows 8-contig).
    // Only lane<->lane^32 exchange needed; 1 shfl + 3 selects per word-pair.
    bf16x8 pf[4];
#pragma unroll
    for (int kk = 0; kk < 4; ++kk) {
      const int qb = 2 * (kk & 1);
      union { unsigned u[4]; bf16x8 v; } pu;
#pragma unroll
      for (int wi = 0; wi < 2; ++wi) {
        unsigned a  = (kk < 2) ? pk0[qb][wi]     : pk1[qb][wi];
        unsigned bv = (kk < 2) ? pk0[qb + 1][wi] : pk1[qb + 1][wi];
        unsigned sv = h ? a : bv;
        unsigned rv = (unsigned)__shfl_xor((int)sv, 32);
        pu.u[wi]     = h ? rv : a;
        pu.u[2 + wi] = h ? bv : rv;
      }
      pf[kk] = pu.v;
    }

    // O[c,j] += V[c,i] * P[i,j]
#pragma unroll
    for (int ct = 0; ct < 8; ++ct) {
      const bf16* vrow = vb + ct * 2048;
      oacc[ct] = mfma32(*(const bf16x8*)(vrow + voff[0]), pf[0], oacc[ct]);
      oacc[ct] = mfma32(*(const bf16x8*)(vrow + voff[1]), pf[1], oacc[ct]);
      oacc[ct] = mfma32(*(const bf16x8*)(vrow + voff[2]), pf[2], oacc[ct]);
      oacc[ct] = mfma32(*(const bf16x8*)(vrow + voff[3]), pf[3], oacc[ct]);
    }

    asm volatile("s_waitcnt vmcnt(0)" ::: "memory");
    __syncthreads();
  }

  // epilogue: out = gamma * O/l + x
  const float ginv = gammap[0] / l_run;
  const float* xb = x + (size_t)b * CC * NN;
  float* ob = out + (size_t)b * CC * NN;
#pragma unroll
  for (int ct = 0; ct < 8; ++ct) {
#pragma unroll
    for (int r = 0; r < 16; ++r) {
      int c = ct * 32 + (r & 3) + 8 * (r >> 2) + 4 * h;
      size_t idx = (size_t)c * NN + j;
      ob[idx] = fmaf(ginv, oacc[ct][r], xb[idx]);
    }
  }
}

extern "C" void kernel_launch(void* const* d_in, const int* in_sizes, int n_in,
                              void* d_out, int out_size, void* d_ws, size_t ws_size,
                              hipStream_t stream) {
  const float* x     = (const float*)d_in[0];
  const float* Wf    = (const float*)d_in[1];
  const float* bfv   = (const float*)d_in[2];
  const float* Wg    = (const float*)d_in[3];
  const float* bg    = (const float*)d_in[4];
  const float* Wh    = (const float*)d_in[5];
  const float* bh    = (const float*)d_in[6];
  const float* gamma = (const float*)d_in[7];
  float* out = (float*)d_out;

  // workspace layout (~21.2 MB); xT lives in d_out (33.5 MB) since out is written last.
  char* ws = (char*)d_ws;
  bf16* fxT  = (bf16*)(ws);                      //  2 MB
  bf16* gxT  = (bf16*)(ws + 2097152);            //  2 MB
  bf16* hx   = (bf16*)(ws + 4194304);            // 16.8 MB
  bf16* Wcat = (bf16*)(ws + 20971520);           // 160 KB
  float* bcat = (float*)(ws + 21135360);         // 1.25 KB
  bf16* xT = (bf16*)d_out;                       // 16.8 MB scratch, dead before k_attn writes

  k_transpose<<<dim3(64, 4, 8), 256, 0, stream>>>(x, xT);
  k_wprep<<<dim3(320), 64, 0, stream>>>(Wf, bfv, Wg, bg, Wh, bh, Wcat, bcat);
  k_proj<<<dim3(256), 256, 0, stream>>>(xT, Wcat, bcat, fxT, gxT, hx);
  k_attn<<<dim3(256), 256, 0, stream>>>(fxT, gxT, hx, x, gamma, out);
}